// Round 5
// baseline (335.543 us; speedup 1.0000x reference)
//
#include <hip/hip_runtime.h>

constexpr int NODES = 50000;
constexpr int EDGES = 600000;
constexpr int DIM = 128;
constexpr int CHUNK = 1024;                            // scan chunk (256 thr x 4)
constexpr int NB_SCAN = (NODES + CHUNK - 1) / CHUNK;   // 49
constexpr int HBINS = 8192;                            // histogram bins per range (32KB LDS)
constexpr int HRANGES = (NODES + HBINS - 1) / HBINS;   // 7
constexpr int HCHUNKS = 8;                             // edge chunks
constexpr int EPC = EDGES / HCHUNKS;                   // 75000

typedef __attribute__((ext_vector_type(8))) short short8v;
typedef __attribute__((ext_vector_type(8))) unsigned short ushort8v;
typedef __attribute__((ext_vector_type(4))) float f32x4;

__device__ __forceinline__ unsigned short f2bf(float f) {
    unsigned int b = __float_as_uint(f);
    b += 0x7fffu + ((b >> 16) & 1u);                   // round-to-nearest-even
    return (unsigned short)(b >> 16);
}

// swizzled LDS byte offset: row stride 256B (128 bf16), 16B slot XOR row&7
__device__ __forceinline__ int swz(int row, int oct) {
    return row * 256 + ((oct ^ (row & 7)) << 4);
}

// ---------- Stage 0: Wt[n][k] = bf16(W[k][n]) ----------
__global__ __launch_bounds__(256) void transpose_w(const float* __restrict__ W,
                                                   unsigned short* __restrict__ Wt) {
    int t = blockIdx.x * 256 + threadIdx.x;            // 16384 total
    int n = t >> 7, k = t & 127;
    Wt[t] = f2bf(W[k * DIM + n]);
}

// ---------- Stage 1: LDS-privatized degree histograms (no global atomics) ---
// block b: arr = b/(R*C) (0=src,1=dst), r = range, c = edge-chunk
__global__ __launch_bounds__(256) void hist_kernel(const int* __restrict__ src,
                                                   const int* __restrict__ dst,
                                                   int* __restrict__ partial) {
    __shared__ int h[HBINS];
    int b = blockIdx.x;
    int arr = b / (HRANGES * HCHUNKS);
    int rc  = b % (HRANGES * HCHUNKS);
    int r = rc / HCHUNKS, c = rc % HCHUNKS;
    int tid = threadIdx.x;
    for (int i = tid; i < HBINS; i += 256) h[i] = 0;
    __syncthreads();
    const int4* idx = reinterpret_cast<const int4*>(arr == 0 ? src : dst);
    int t0 = c * (EPC / 4);
    int base = r * HBINS;
    for (int t = t0 + tid; t < t0 + EPC / 4; t += 256) {
        int4 v = idx[t];
        int a0 = v.x - base; if ((unsigned)a0 < (unsigned)HBINS) atomicAdd(&h[a0], 1);
        int a1 = v.y - base; if ((unsigned)a1 < (unsigned)HBINS) atomicAdd(&h[a1], 1);
        int a2 = v.z - base; if ((unsigned)a2 < (unsigned)HBINS) atomicAdd(&h[a2], 1);
        int a3 = v.w - base; if ((unsigned)a3 < (unsigned)HBINS) atomicAdd(&h[a3], 1);
    }
    __syncthreads();
    int* outp = partial + (size_t)b * HBINS;
    for (int i = tid; i < HBINS; i += 256) outp[i] = h[i];
}

// ---------- Stage 2: deg = sum of partials ----------
__global__ __launch_bounds__(256) void reduce_deg(const int* __restrict__ partial,
                                                  int* __restrict__ deg_out,
                                                  int* __restrict__ deg_in) {
    int n = blockIdx.x * 256 + threadIdx.x;
    if (n >= NODES) return;
    int r = n / HBINS, bin = n % HBINS;
    int s0 = 0, s1 = 0;
    #pragma unroll
    for (int c = 0; c < HCHUNKS; ++c) {
        s0 += partial[((size_t)(0 * HRANGES + r) * HCHUNKS + c) * HBINS + bin];
        s1 += partial[((size_t)(1 * HRANGES + r) * HCHUNKS + c) * HBINS + bin];
    }
    deg_out[n] = s0;
    deg_in[n] = s1;
}

// ---------- Stage 3a: per-chunk totals for row_start scan ----------
__global__ __launch_bounds__(256) void scan_partials(const int* __restrict__ deg_in,
                                                     int* __restrict__ scan_part) {
    __shared__ int wsum[4];
    int tid = threadIdx.x, lane = tid & 63, wid = tid >> 6;
    int base = blockIdx.x * CHUNK + tid * 4;
    int s = 0;
    #pragma unroll
    for (int i = 0; i < 4; ++i)
        if (base + i < NODES) s += deg_in[base + i];
    #pragma unroll
    for (int off = 32; off; off >>= 1) s += __shfl_down(s, off, 64);
    if (lane == 0) wsum[wid] = s;
    __syncthreads();
    if (tid == 0)
        scan_part[blockIdx.x] = wsum[0] + wsum[1] + wsum[2] + wsum[3];
}

// ---------- Stage 3b: chunk-local exclusive scan + global offset ----------
__global__ __launch_bounds__(256) void scan_chunks(const int* __restrict__ deg_in,
                                                   const int* __restrict__ scan_part,
                                                   int* __restrict__ row_start) {
    __shared__ int wsum[4];
    __shared__ int blockoff_s;
    int b = blockIdx.x, tid = threadIdx.x, lane = tid & 63, wid = tid >> 6;
    if (wid == 0) {
        int v = (lane < b) ? scan_part[lane] : 0;      // NB_SCAN=49 <= 64
        #pragma unroll
        for (int off = 32; off; off >>= 1) v += __shfl_down(v, off, 64);
        if (lane == 0) blockoff_s = v;
    }
    int base = b * CHUNK + tid * 4;
    int v[4];
    int s = 0;
    #pragma unroll
    for (int i = 0; i < 4; ++i) {
        v[i] = (base + i < NODES) ? deg_in[base + i] : 0;
        s += v[i];
    }
    int incl = s;
    #pragma unroll
    for (int off = 1; off < 64; off <<= 1) {
        int t = __shfl_up(incl, off, 64);
        if (lane >= off) incl += t;
    }
    if (lane == 63) wsum[wid] = incl;
    __syncthreads();
    int wbase = 0;
    for (int w = 0; w < wid; ++w) wbase += wsum[w];
    int run = blockoff_s + wbase + incl - s;
    #pragma unroll
    for (int i = 0; i < 4; ++i) {
        if (base + i < NODES) row_start[base + i] = run;
        run += v[i];
    }
}

// ---------- Stage 4: bucket edges by dst via LDS cursors (no global atomics) -
// block (r,c): cursor[bin] = row_start[bin] + sum_{c'<c} partial_in[r][c'][bin]
__global__ __launch_bounds__(256) void bucket_lds(const int* __restrict__ src,
                                                  const int* __restrict__ dst,
                                                  const int* __restrict__ row_start,
                                                  const int* __restrict__ partial_in,
                                                  int* __restrict__ csr_src) {
    __shared__ int cur[HBINS];
    int r = blockIdx.x / HCHUNKS, c = blockIdx.x % HCHUNKS;
    int tid = threadIdx.x;
    int base = r * HBINS;
    for (int i = tid; i < HBINS; i += 256) {
        int n = base + i;
        int v = (n < NODES) ? row_start[n] : 0;
        for (int cc = 0; cc < c; ++cc)
            v += partial_in[((size_t)r * HCHUNKS + cc) * HBINS + i];
        cur[i] = v;
    }
    __syncthreads();
    int e0 = c * EPC;
    for (int e = e0 + tid; e < e0 + EPC; e += 256) {
        int d = dst[e] - base;
        if ((unsigned)d < (unsigned)HBINS) {
            int pos = atomicAdd(&cur[d], 1);           // LDS atomic
            csr_src[pos] = src[e];
        }
    }
}

// ---------- Stage 5: H = bf16((X * rsqrt(out_deg)) @ W) via MFMA ----------
// 256 thr = 4 waves; BM=64 (wave w owns rows w*16..w*16+15), N=128, K=128.
__global__ __launch_bounds__(256) void gemm_mfma(const float* __restrict__ X,
                                                 const int* __restrict__ deg_out,
                                                 const unsigned short* __restrict__ Wt,
                                                 unsigned short* __restrict__ H) {
    __shared__ char XsB[64 * 256];    // 64 rows x 128 bf16, swizzled (16KB)
    __shared__ char WsB[128 * 256];   // Wt[n][k] bf16, swizzled (32KB)
    int tid = threadIdx.x;
    int row0 = blockIdx.x * 64;

    // stage Wt (coalesced 16B)
    for (int t = tid; t < 128 * 16; t += 256) {
        int n = t >> 4, o = t & 15;
        ushort8v wv = *reinterpret_cast<const ushort8v*>(Wt + n * DIM + o * 8);
        *reinterpret_cast<ushort8v*>(WsB + swz(n, o)) = wv;
    }
    // stage X: scale rows by rsqrt(clamp(out_deg,1)), convert bf16
    for (int t = tid; t < 64 * 16; t += 256) {
        int r = t >> 4, o = t & 15;
        int node = row0 + r;
        float4 v0 = make_float4(0.f, 0.f, 0.f, 0.f), v1 = v0;
        float sc = 0.f;
        if (node < NODES) {
            const float4* rp = reinterpret_cast<const float4*>(X + (size_t)node * DIM);
            v0 = rp[o * 2];
            v1 = rp[o * 2 + 1];
            int dg = deg_out[node];
            sc = rsqrtf((float)(dg > 0 ? dg : 1));
        }
        ushort8v h;
        h[0] = f2bf(v0.x * sc); h[1] = f2bf(v0.y * sc);
        h[2] = f2bf(v0.z * sc); h[3] = f2bf(v0.w * sc);
        h[4] = f2bf(v1.x * sc); h[5] = f2bf(v1.y * sc);
        h[6] = f2bf(v1.z * sc); h[7] = f2bf(v1.w * sc);
        *reinterpret_cast<ushort8v*>(XsB + swz(r, o)) = h;
    }
    __syncthreads();

    int w = tid >> 6, l = tid & 63;
    int lr = l & 15, lg = l >> 4;
    f32x4 acc[8];
    #pragma unroll
    for (int nt = 0; nt < 8; ++nt) acc[nt] = (f32x4){0.f, 0.f, 0.f, 0.f};
    #pragma unroll
    for (int kb = 0; kb < 4; ++kb) {
        short8v a = *reinterpret_cast<short8v*>(XsB + swz(w * 16 + lr, kb * 4 + lg));
        #pragma unroll
        for (int nt = 0; nt < 8; ++nt) {
            short8v bfr = *reinterpret_cast<short8v*>(WsB + swz(nt * 16 + lr, kb * 4 + lg));
            acc[nt] = __builtin_amdgcn_mfma_f32_16x16x32_bf16(a, bfr, acc[nt], 0, 0, 0);
        }
    }
    // scatter D (bf16) into own 16 rows of XsB; D: row=(l>>4)*4+reg, col=lane&15
    #pragma unroll
    for (int nt = 0; nt < 8; ++nt) {
        int col = nt * 16 + lr;
        #pragma unroll
        for (int rg = 0; rg < 4; ++rg) {
            int m = w * 16 + lg * 4 + rg;
            int byte = m * 256 + (((col >> 3) ^ (m & 7)) << 4) + (col & 7) * 2;
            *reinterpret_cast<unsigned short*>(XsB + byte) = f2bf(acc[nt][rg]);
        }
    }
    __syncthreads();
    // coalesced write-out
    for (int t = tid; t < 64 * 16; t += 256) {
        int r = t >> 4, o = t & 15;
        int node = row0 + r;
        if (node < NODES)
            *reinterpret_cast<ushort8v*>(H + (size_t)node * DIM + o * 8) =
                *reinterpret_cast<ushort8v*>(XsB + swz(r, o));
    }
}

// ---------- Stage 6: out[n] = relu(rsqrt(in_deg)*sum H[src] + b) ----------
__global__ __launch_bounds__(256) void gather_kernel(const unsigned int* __restrict__ Hu,
                                                     const int* __restrict__ row_start,
                                                     const int* __restrict__ deg_in,
                                                     const int* __restrict__ csr_src,
                                                     const float* __restrict__ bias,
                                                     float* __restrict__ out) {
    int gw = (blockIdx.x * 256 + threadIdx.x) >> 6;
    int lane = threadIdx.x & 63;
    if (gw >= NODES) return;
    int start = row_start[gw];
    int deg = deg_in[gw];
    float ax = 0.f, ay = 0.f;
    for (int i0 = 0; i0 < deg; i0 += 64) {
        int nv = min(64, deg - i0);
        int sv = 0;
        if (i0 + lane < deg) sv = csr_src[start + i0 + lane];
        for (int i = 0; i < nv; ++i) {
            int s = __shfl(sv, i, 64);
            unsigned int u = Hu[(size_t)s * 64 + lane];
            ax += __uint_as_float(u << 16);
            ay += __uint_as_float(u & 0xffff0000u);
        }
    }
    float sc = rsqrtf((float)(deg > 0 ? deg : 1));
    float2 bb = reinterpret_cast<const float2*>(bias)[lane];
    float2 o;
    o.x = fmaxf(ax * sc + bb.x, 0.f);
    o.y = fmaxf(ay * sc + bb.y, 0.f);
    reinterpret_cast<float2*>(out)[(size_t)gw * 64 + lane] = o;
}

extern "C" void kernel_launch(void* const* d_in, const int* in_sizes, int n_in,
                              void* d_out, int out_size, void* d_ws, size_t ws_size,
                              hipStream_t stream) {
    const float* feat = (const float*)d_in[0];
    const float* W    = (const float*)d_in[1];
    const float* b    = (const float*)d_in[2];
    const int*   src  = (const int*)d_in[3];
    const int*   dst  = (const int*)d_in[4];
    float* out = (float*)d_out;

    char* p = (char*)d_ws;
    unsigned short* H  = (unsigned short*)p;  p += (size_t)NODES * DIM * 2;       // 12.8MB
    unsigned short* Wt = (unsigned short*)p;  p += (size_t)DIM * DIM * 2;         // 32KB
    int* deg_out   = (int*)p;  p += (size_t)NODES * 4;
    int* deg_in    = (int*)p;  p += (size_t)NODES * 4;
    int* row_start = (int*)p;  p += (size_t)NODES * 4;
    int* scan_part = (int*)p;  p += 256;
    int* partial   = (int*)p;  p += (size_t)2 * HRANGES * HCHUNKS * HBINS * 4;    // 3.67MB
    int* csr_src   = (int*)p;                                                     // 2.4MB
    const int* partial_in = partial + (size_t)HRANGES * HCHUNKS * HBINS;

    transpose_w<<<DIM * DIM / 256, 256, 0, stream>>>(W, Wt);
    hist_kernel<<<2 * HRANGES * HCHUNKS, 256, 0, stream>>>(src, dst, partial);
    reduce_deg<<<(NODES + 255) / 256, 256, 0, stream>>>(partial, deg_out, deg_in);
    scan_partials<<<NB_SCAN, 256, 0, stream>>>(deg_in, scan_part);
    scan_chunks<<<NB_SCAN, 256, 0, stream>>>(deg_in, scan_part, row_start);
    bucket_lds<<<HRANGES * HCHUNKS, 256, 0, stream>>>(src, dst, row_start, partial_in, csr_src);
    gemm_mfma<<<(NODES + 63) / 64, 256, 0, stream>>>(feat, deg_out, Wt, H);
    gather_kernel<<<(NODES * 64 + 255) / 256, 256, 0, stream>>>(
        (const unsigned int*)H, row_start, deg_in, csr_src, b, out);
}

// Round 7
// 185.487 us; speedup vs baseline: 1.8090x; 1.8090x over previous
//
#include <hip/hip_runtime.h>

constexpr int NODES = 50000;
constexpr int EDGES = 600000;
constexpr int DIM = 128;
constexpr int CHUNK = 1024;                            // scan chunk (256 thr x 4)
constexpr int NB_SCAN = (NODES + CHUNK - 1) / CHUNK;   // 49
constexpr int HBINS = 8192;                            // bins per range (32KB LDS)
constexpr int HRANGES = (NODES + HBINS - 1) / HBINS;   // 7
constexpr int HC = 40;                                 // edge chunks
constexpr int EPC = EDGES / HC;                        // 15000
constexpr int EPC4 = EPC / 4;                          // 3750

typedef __attribute__((ext_vector_type(8))) short short8v;
typedef __attribute__((ext_vector_type(8))) unsigned short ushort8v;
typedef __attribute__((ext_vector_type(4))) float f32x4;

__device__ __forceinline__ unsigned short f2bf(float f) {
    unsigned int b = __float_as_uint(f);
    b += 0x7fffu + ((b >> 16) & 1u);                   // round-to-nearest-even
    return (unsigned short)(b >> 16);
}

// swizzled LDS byte offset: row stride 256B (128 bf16), 16B slot XOR row&7
__device__ __forceinline__ int swz(int row, int oct) {
    return row * 256 + ((oct ^ (row & 7)) << 4);
}

// ---------- Stage 0: Wt[n][k] = bf16(W[k][n]) ----------
__global__ __launch_bounds__(256) void transpose_w(const float* __restrict__ W,
                                                   unsigned short* __restrict__ Wt) {
    int t = blockIdx.x * 256 + threadIdx.x;
    int n = t >> 7, k = t & 127;
    Wt[t] = f2bf(W[k * DIM + n]);
}

// ---------- Stage 1: LDS-privatized degree histograms (no global atomics) ---
// block b: arr = b/(R*HC) (0=src,1=dst), r = range, c = edge-chunk
__global__ __launch_bounds__(256) void hist_kernel(const int* __restrict__ src,
                                                   const int* __restrict__ dst,
                                                   unsigned short* __restrict__ partial) {
    __shared__ int h[HBINS];
    int b = blockIdx.x;
    int arr = b / (HRANGES * HC);
    int rc  = b % (HRANGES * HC);
    int r = rc / HC, c = rc % HC;
    int tid = threadIdx.x;
    for (int i = tid; i < HBINS; i += 256) h[i] = 0;
    __syncthreads();
    const int4* idx = reinterpret_cast<const int4*>(arr == 0 ? src : dst);
    int t0 = c * EPC4;
    int base = r * HBINS;
    for (int t = t0 + tid; t < t0 + EPC4; t += 256) {
        int4 v = idx[t];
        int a0 = v.x - base; if ((unsigned)a0 < (unsigned)HBINS) atomicAdd(&h[a0], 1);
        int a1 = v.y - base; if ((unsigned)a1 < (unsigned)HBINS) atomicAdd(&h[a1], 1);
        int a2 = v.z - base; if ((unsigned)a2 < (unsigned)HBINS) atomicAdd(&h[a2], 1);
        int a3 = v.w - base; if ((unsigned)a3 < (unsigned)HBINS) atomicAdd(&h[a3], 1);
    }
    __syncthreads();
    unsigned short* outp = partial + (size_t)b * HBINS;
    for (int i = tid; i < HBINS; i += 256) outp[i] = (unsigned short)h[i];
}

// ---------- Stage 2: deg = sum of per-chunk partials ----------
__global__ __launch_bounds__(256) void reduce_deg(const unsigned short* __restrict__ partial,
                                                  int* __restrict__ deg_out,
                                                  int* __restrict__ deg_in) {
    int n = blockIdx.x * 256 + threadIdx.x;            // n over R*HBINS
    if (n >= NODES) return;
    int r = n >> 13, bin = n & (HBINS - 1);
    const unsigned short* ps = partial;
    const unsigned short* pd = partial + (size_t)HRANGES * HC * HBINS;
    int s0 = 0, s1 = 0;
    #pragma unroll 8
    for (int c = 0; c < HC; ++c) {
        s0 += ps[(size_t)(r * HC + c) * HBINS + bin];
        s1 += pd[(size_t)(r * HC + c) * HBINS + bin];
    }
    deg_out[n] = s0;
    deg_in[n] = s1;
}

// ---------- Stage 3a: per-chunk totals for row_start scan ----------
__global__ __launch_bounds__(256) void scan_partials(const int* __restrict__ deg_in,
                                                     int* __restrict__ scan_part) {
    __shared__ int wsum[4];
    int tid = threadIdx.x, lane = tid & 63, wid = tid >> 6;
    int base = blockIdx.x * CHUNK + tid * 4;
    int s = 0;
    #pragma unroll
    for (int i = 0; i < 4; ++i)
        if (base + i < NODES) s += deg_in[base + i];
    #pragma unroll
    for (int off = 32; off; off >>= 1) s += __shfl_down(s, off, 64);
    if (lane == 0) wsum[wid] = s;
    __syncthreads();
    if (tid == 0)
        scan_part[blockIdx.x] = wsum[0] + wsum[1] + wsum[2] + wsum[3];
}

// ---------- Stage 3b: chunk-local exclusive scan + global offset ----------
__global__ __launch_bounds__(256) void scan_chunks(const int* __restrict__ deg_in,
                                                   const int* __restrict__ scan_part,
                                                   int* __restrict__ row_start) {
    __shared__ int wsum[4];
    __shared__ int blockoff_s;
    int b = blockIdx.x, tid = threadIdx.x, lane = tid & 63, wid = tid >> 6;
    if (wid == 0) {
        int v = (lane < b) ? scan_part[lane] : 0;      // NB_SCAN=49 <= 64
        #pragma unroll
        for (int off = 32; off; off >>= 1) v += __shfl_down(v, off, 64);
        if (lane == 0) blockoff_s = v;
    }
    int base = b * CHUNK + tid * 4;
    int v[4];
    int s = 0;
    #pragma unroll
    for (int i = 0; i < 4; ++i) {
        v[i] = (base + i < NODES) ? deg_in[base + i] : 0;
        s += v[i];
    }
    int incl = s;
    #pragma unroll
    for (int off = 1; off < 64; off <<= 1) {
        int t = __shfl_up(incl, off, 64);
        if (lane >= off) incl += t;
    }
    if (lane == 63) wsum[wid] = incl;
    __syncthreads();
    int wbase = 0;
    for (int w = 0; w < wid; ++w) wbase += wsum[w];
    int run = blockoff_s + wbase + incl - s;
    #pragma unroll
    for (int i = 0; i < 4; ++i) {
        if (base + i < NODES) row_start[base + i] = run;
        run += v[i];
    }
}

// ---------- Stage 4a: cumoff[r][c][bin] = sum_{c'<c} partial_dst[r][c'][bin] -
__global__ __launch_bounds__(256) void coff_kernel(const unsigned short* __restrict__ partial_dst,
                                                   unsigned short* __restrict__ cumoff) {
    int n = blockIdx.x * 256 + threadIdx.x;            // over R*HBINS = 57344
    if (n >= HRANGES * HBINS) return;
    int r = n >> 13, bin = n & (HBINS - 1);
    int run = 0;
    #pragma unroll 8
    for (int c = 0; c < HC; ++c) {
        size_t idx = (size_t)(r * HC + c) * HBINS + bin;
        cumoff[idx] = (unsigned short)run;
        run += partial_dst[idx];
    }
}

// ---------- Stage 4b: bucket edges by dst via LDS cursors ----------
__global__ __launch_bounds__(256) void bucket_lds(const int* __restrict__ src,
                                                  const int* __restrict__ dst,
                                                  const int* __restrict__ row_start,
                                                  const unsigned short* __restrict__ cumoff,
                                                  int* __restrict__ csr_src) {
    __shared__ int cur[HBINS];
    int r = blockIdx.x / HC, c = blockIdx.x % HC;
    int tid = threadIdx.x;
    int base = r * HBINS;
    const unsigned short* co = cumoff + (size_t)(r * HC + c) * HBINS;
    for (int i = tid; i < HBINS; i += 256) {
        int n = base + i;
        int rs = (n < NODES) ? row_start[n] : 0;
        cur[i] = rs + (int)co[i];
    }
    __syncthreads();
    const int4* dst4 = reinterpret_cast<const int4*>(dst);
    const int4* src4 = reinterpret_cast<const int4*>(src);
    int t0 = c * EPC4;
    for (int t = t0 + tid; t < t0 + EPC4; t += 256) {
        int4 dv = dst4[t];
        int4 sv = src4[t];
        int d;
        d = dv.x - base; if ((unsigned)d < (unsigned)HBINS) csr_src[atomicAdd(&cur[d], 1)] = sv.x;
        d = dv.y - base; if ((unsigned)d < (unsigned)HBINS) csr_src[atomicAdd(&cur[d], 1)] = sv.y;
        d = dv.z - base; if ((unsigned)d < (unsigned)HBINS) csr_src[atomicAdd(&cur[d], 1)] = sv.z;
        d = dv.w - base; if ((unsigned)d < (unsigned)HBINS) csr_src[atomicAdd(&cur[d], 1)] = sv.w;
    }
}

// ---------- Stage 5: H = bf16((X * rsqrt(out_deg)) @ W) via MFMA ----------
__global__ __launch_bounds__(256) void gemm_mfma(const float* __restrict__ X,
                                                 const int* __restrict__ deg_out,
                                                 const unsigned short* __restrict__ Wt,
                                                 unsigned short* __restrict__ H) {
    __shared__ char XsB[64 * 256];    // 64 rows x 128 bf16, swizzled (16KB)
    __shared__ char WsB[128 * 256];   // Wt[n][k] bf16, swizzled (32KB)
    int tid = threadIdx.x;
    int row0 = blockIdx.x * 64;

    for (int t = tid; t < 128 * 16; t += 256) {
        int n = t >> 4, o = t & 15;
        ushort8v wv = *reinterpret_cast<const ushort8v*>(Wt + n * DIM + o * 8);
        *reinterpret_cast<ushort8v*>(WsB + swz(n, o)) = wv;
    }
    for (int t = tid; t < 64 * 16; t += 256) {
        int r = t >> 4, o = t & 15;
        int node = row0 + r;
        float4 v0 = make_float4(0.f, 0.f, 0.f, 0.f), v1 = v0;
        float sc = 0.f;
        if (node < NODES) {
            const float4* rp = reinterpret_cast<const float4*>(X + (size_t)node * DIM);
            v0 = rp[o * 2];
            v1 = rp[o * 2 + 1];
            int dg = deg_out[node];
            sc = rsqrtf((float)(dg > 0 ? dg : 1));
        }
        ushort8v h;
        h[0] = f2bf(v0.x * sc); h[1] = f2bf(v0.y * sc);
        h[2] = f2bf(v0.z * sc); h[3] = f2bf(v0.w * sc);
        h[4] = f2bf(v1.x * sc); h[5] = f2bf(v1.y * sc);
        h[6] = f2bf(v1.z * sc); h[7] = f2bf(v1.w * sc);
        *reinterpret_cast<ushort8v*>(XsB + swz(r, o)) = h;
    }
    __syncthreads();

    int w = tid >> 6, l = tid & 63;
    int lr = l & 15, lg = l >> 4;
    f32x4 acc[8];
    #pragma unroll
    for (int nt = 0; nt < 8; ++nt) acc[nt] = (f32x4){0.f, 0.f, 0.f, 0.f};
    #pragma unroll
    for (int kb = 0; kb < 4; ++kb) {
        short8v a = *reinterpret_cast<short8v*>(XsB + swz(w * 16 + lr, kb * 4 + lg));
        #pragma unroll
        for (int nt = 0; nt < 8; ++nt) {
            short8v bfr = *reinterpret_cast<short8v*>(WsB + swz(nt * 16 + lr, kb * 4 + lg));
            acc[nt] = __builtin_amdgcn_mfma_f32_16x16x32_bf16(a, bfr, acc[nt], 0, 0, 0);
        }
    }
    #pragma unroll
    for (int nt = 0; nt < 8; ++nt) {
        int col = nt * 16 + lr;
        #pragma unroll
        for (int rg = 0; rg < 4; ++rg) {
            int m = w * 16 + lg * 4 + rg;
            int byte = m * 256 + (((col >> 3) ^ (m & 7)) << 4) + (col & 7) * 2;
            *reinterpret_cast<unsigned short*>(XsB + byte) = f2bf(acc[nt][rg]);
        }
    }
    __syncthreads();
    for (int t = tid; t < 64 * 16; t += 256) {
        int r = t >> 4, o = t & 15;
        int node = row0 + r;
        if (node < NODES)
            *reinterpret_cast<ushort8v*>(H + (size_t)node * DIM + o * 8) =
                *reinterpret_cast<ushort8v*>(XsB + swz(r, o));
    }
}

// ---------- Stage 6: out[n] = relu(rsqrt(in_deg)*sum H[src] + b) ----------
__global__ __launch_bounds__(256) void gather_kernel(const unsigned int* __restrict__ Hu,
                                                     const int* __restrict__ row_start,
                                                     const int* __restrict__ deg_in,
                                                     const int* __restrict__ csr_src,
                                                     const float* __restrict__ bias,
                                                     float* __restrict__ out) {
    int gw = (blockIdx.x * 256 + threadIdx.x) >> 6;
    int lane = threadIdx.x & 63;
    if (gw >= NODES) return;
    int start = row_start[gw];
    int deg = deg_in[gw];
    float ax = 0.f, ay = 0.f;
    for (int i0 = 0; i0 < deg; i0 += 64) {
        int nv = min(64, deg - i0);
        int sv = 0;
        if (i0 + lane < deg) sv = csr_src[start + i0 + lane];
        for (int i = 0; i < nv; ++i) {
            int s = __shfl(sv, i, 64);
            unsigned int u = Hu[(size_t)s * 64 + lane];
            ax += __uint_as_float(u << 16);
            ay += __uint_as_float(u & 0xffff0000u);
        }
    }
    float sc = rsqrtf((float)(deg > 0 ? deg : 1));
    float2 bb = reinterpret_cast<const float2*>(bias)[lane];
    float2 o;
    o.x = fmaxf(ax * sc + bb.x, 0.f);
    o.y = fmaxf(ay * sc + bb.y, 0.f);
    reinterpret_cast<float2*>(out)[(size_t)gw * 64 + lane] = o;
}

extern "C" void kernel_launch(void* const* d_in, const int* in_sizes, int n_in,
                              void* d_out, int out_size, void* d_ws, size_t ws_size,
                              hipStream_t stream) {
    const float* feat = (const float*)d_in[0];
    const float* W    = (const float*)d_in[1];
    const float* b    = (const float*)d_in[2];
    const int*   src  = (const int*)d_in[3];
    const int*   dst  = (const int*)d_in[4];
    float* out = (float*)d_out;

    constexpr size_t PART_ELEMS = (size_t)HRANGES * HC * HBINS;   // 2,293,760

    char* p = (char*)d_ws;
    // Region A: partial_src | partial_dst | cumoff (3x PART ushort = 13.76MB).
    // H (12.8MB) aliases this region — partial/cumoff are dead before gemm_mfma.
    unsigned short* partial = (unsigned short*)p;
    unsigned short* cumoff  = partial + 2 * PART_ELEMS;
    unsigned short* H       = (unsigned short*)p;
    p += 3 * PART_ELEMS * sizeof(unsigned short);
    unsigned short* Wt = (unsigned short*)p;  p += (size_t)DIM * DIM * 2;
    int* deg_out   = (int*)p;  p += (size_t)NODES * 4;
    int* deg_in    = (int*)p;  p += (size_t)NODES * 4;
    int* row_start = (int*)p;  p += (size_t)NODES * 4;
    int* scan_part = (int*)p;  p += 256;
    int* csr_src   = (int*)p;                                     // 2.4MB
    const unsigned short* partial_dst = partial + PART_ELEMS;

    transpose_w<<<DIM * DIM / 256, 256, 0, stream>>>(W, Wt);
    hist_kernel<<<2 * HRANGES * HC, 256, 0, stream>>>(src, dst, partial);
    reduce_deg<<<(HRANGES * HBINS) / 256, 256, 0, stream>>>(partial, deg_out, deg_in);
    scan_partials<<<NB_SCAN, 256, 0, stream>>>(deg_in, scan_part);
    scan_chunks<<<NB_SCAN, 256, 0, stream>>>(deg_in, scan_part, row_start);
    coff_kernel<<<(HRANGES * HBINS) / 256, 256, 0, stream>>>(partial_dst, cumoff);
    bucket_lds<<<HRANGES * HC, 256, 0, stream>>>(src, dst, row_start, cumoff, csr_src);
    gemm_mfma<<<(NODES + 63) / 64, 256, 0, stream>>>(feat, deg_out, Wt, H);
    gather_kernel<<<(NODES * 64 + 255) / 256, 256, 0, stream>>>(
        (const unsigned int*)H, row_start, deg_in, csr_src, b, out);
}

// Round 8
// 164.704 us; speedup vs baseline: 2.0373x; 1.1262x over previous
//
#include <hip/hip_runtime.h>

constexpr int NODES = 50000;
constexpr int EDGES = 600000;
constexpr int DIM = 128;
constexpr int CHUNK = 1024;                            // scan chunk (256 thr x 4)
constexpr int NB_SCAN = (NODES + CHUNK - 1) / CHUNK;   // 49
constexpr int HBINS = 8192;                            // bins per range (32KB LDS)
constexpr int HRANGES = (NODES + HBINS - 1) / HBINS;   // 7
constexpr int HC = 40;                                 // edge chunks
constexpr int EPC = EDGES / HC;                        // 15000
constexpr int EPC4 = EPC / 4;                          // 3750

typedef __attribute__((ext_vector_type(8))) short short8v;
typedef __attribute__((ext_vector_type(8))) unsigned short ushort8v;
typedef __attribute__((ext_vector_type(4))) float f32x4;

__device__ __forceinline__ unsigned short f2bf(float f) {
    unsigned int b = __float_as_uint(f);
    b += 0x7fffu + ((b >> 16) & 1u);                   // round-to-nearest-even
    return (unsigned short)(b >> 16);
}

// swizzled LDS byte offset: row stride 256B (128 bf16), 16B slot XOR row&7
__device__ __forceinline__ int swz(int row, int oct) {
    return row * 256 + ((oct ^ (row & 7)) << 4);
}

// ---------- Stage 0: Wt[n][k] = bf16(W[k][n]) ----------
__global__ __launch_bounds__(256) void transpose_w(const float* __restrict__ W,
                                                   unsigned short* __restrict__ Wt) {
    int t = blockIdx.x * 256 + threadIdx.x;
    int n = t >> 7, k = t & 127;
    Wt[t] = f2bf(W[k * DIM + n]);
}

// ---------- Stage 1: LDS-privatized degree histograms (no global atomics) ---
// block b: arr = b/(R*HC) (0=src,1=dst), r = range, c = edge-chunk
__global__ __launch_bounds__(256) void hist_kernel(const int* __restrict__ src,
                                                   const int* __restrict__ dst,
                                                   unsigned short* __restrict__ partial) {
    __shared__ int h[HBINS];
    int b = blockIdx.x;
    int arr = b / (HRANGES * HC);
    int rc  = b % (HRANGES * HC);
    int r = rc / HC, c = rc % HC;
    int tid = threadIdx.x;
    for (int i = tid; i < HBINS; i += 256) h[i] = 0;
    __syncthreads();
    const int4* idx = reinterpret_cast<const int4*>(arr == 0 ? src : dst);
    int t0 = c * EPC4;
    int base = r * HBINS;
    for (int t = t0 + tid; t < t0 + EPC4; t += 256) {
        int4 v = idx[t];
        int a0 = v.x - base; if ((unsigned)a0 < (unsigned)HBINS) atomicAdd(&h[a0], 1);
        int a1 = v.y - base; if ((unsigned)a1 < (unsigned)HBINS) atomicAdd(&h[a1], 1);
        int a2 = v.z - base; if ((unsigned)a2 < (unsigned)HBINS) atomicAdd(&h[a2], 1);
        int a3 = v.w - base; if ((unsigned)a3 < (unsigned)HBINS) atomicAdd(&h[a3], 1);
    }
    __syncthreads();
    unsigned short* outp = partial + (size_t)b * HBINS;
    for (int i = tid; i < HBINS; i += 256) outp[i] = (unsigned short)h[i];
}

// ---------- Stage 2: fused degree-reduce + cumulative chunk offsets ----------
// deg_out[n] = sum_c partial_src; cumoff[r][c][bin] = prefix of partial_dst;
// deg_in[n] = total of partial_dst.
__global__ __launch_bounds__(256) void deg_coff(const unsigned short* __restrict__ partial,
                                                int* __restrict__ deg_out,
                                                int* __restrict__ deg_in,
                                                unsigned short* __restrict__ cumoff) {
    int n = blockIdx.x * 256 + threadIdx.x;            // over R*HBINS = 57344
    if (n >= HRANGES * HBINS) return;
    int r = n >> 13, bin = n & (HBINS - 1);
    const unsigned short* ps = partial;
    const unsigned short* pd = partial + (size_t)HRANGES * HC * HBINS;
    int s0 = 0, run = 0;
    #pragma unroll 8
    for (int c = 0; c < HC; ++c) {
        size_t idx = (size_t)(r * HC + c) * HBINS + bin;
        s0 += ps[idx];
        cumoff[idx] = (unsigned short)run;
        run += pd[idx];
    }
    if (n < NODES) {
        deg_out[n] = s0;
        deg_in[n] = run;
    }
}

// ---------- Stage 3a: per-chunk totals for row_start scan ----------
__global__ __launch_bounds__(256) void scan_partials(const int* __restrict__ deg_in,
                                                     int* __restrict__ scan_part) {
    __shared__ int wsum[4];
    int tid = threadIdx.x, lane = tid & 63, wid = tid >> 6;
    int base = blockIdx.x * CHUNK + tid * 4;
    int s = 0;
    #pragma unroll
    for (int i = 0; i < 4; ++i)
        if (base + i < NODES) s += deg_in[base + i];
    #pragma unroll
    for (int off = 32; off; off >>= 1) s += __shfl_down(s, off, 64);
    if (lane == 0) wsum[wid] = s;
    __syncthreads();
    if (tid == 0)
        scan_part[blockIdx.x] = wsum[0] + wsum[1] + wsum[2] + wsum[3];
}

// ---------- Stage 3b: chunk-local exclusive scan + global offset ----------
__global__ __launch_bounds__(256) void scan_chunks(const int* __restrict__ deg_in,
                                                   const int* __restrict__ scan_part,
                                                   int* __restrict__ row_start) {
    __shared__ int wsum[4];
    __shared__ int blockoff_s;
    int b = blockIdx.x, tid = threadIdx.x, lane = tid & 63, wid = tid >> 6;
    if (wid == 0) {
        int v = (lane < b) ? scan_part[lane] : 0;      // NB_SCAN=49 <= 64
        #pragma unroll
        for (int off = 32; off; off >>= 1) v += __shfl_down(v, off, 64);
        if (lane == 0) blockoff_s = v;
    }
    int base = b * CHUNK + tid * 4;
    int v[4];
    int s = 0;
    #pragma unroll
    for (int i = 0; i < 4; ++i) {
        v[i] = (base + i < NODES) ? deg_in[base + i] : 0;
        s += v[i];
    }
    int incl = s;
    #pragma unroll
    for (int off = 1; off < 64; off <<= 1) {
        int t = __shfl_up(incl, off, 64);
        if (lane >= off) incl += t;
    }
    if (lane == 63) wsum[wid] = incl;
    __syncthreads();
    int wbase = 0;
    for (int w = 0; w < wid; ++w) wbase += wsum[w];
    int run = blockoff_s + wbase + incl - s;
    #pragma unroll
    for (int i = 0; i < 4; ++i) {
        if (base + i < NODES) row_start[base + i] = run;
        run += v[i];
    }
}

// ---------- Stage 4: bucket edges by dst via LDS cursors ----------
__global__ __launch_bounds__(256) void bucket_lds(const int* __restrict__ src,
                                                  const int* __restrict__ dst,
                                                  const int* __restrict__ row_start,
                                                  const unsigned short* __restrict__ cumoff,
                                                  int* __restrict__ csr_src) {
    __shared__ int cur[HBINS];
    int r = blockIdx.x / HC, c = blockIdx.x % HC;
    int tid = threadIdx.x;
    int base = r * HBINS;
    const unsigned short* co = cumoff + (size_t)(r * HC + c) * HBINS;
    for (int i = tid; i < HBINS; i += 256) {
        int n = base + i;
        int rs = (n < NODES) ? row_start[n] : 0;
        cur[i] = rs + (int)co[i];
    }
    __syncthreads();
    const int4* dst4 = reinterpret_cast<const int4*>(dst);
    const int4* src4 = reinterpret_cast<const int4*>(src);
    int t0 = c * EPC4;
    for (int t = t0 + tid; t < t0 + EPC4; t += 256) {
        int4 dv = dst4[t];
        int4 sv = src4[t];
        int d;
        d = dv.x - base; if ((unsigned)d < (unsigned)HBINS) csr_src[atomicAdd(&cur[d], 1)] = sv.x;
        d = dv.y - base; if ((unsigned)d < (unsigned)HBINS) csr_src[atomicAdd(&cur[d], 1)] = sv.y;
        d = dv.z - base; if ((unsigned)d < (unsigned)HBINS) csr_src[atomicAdd(&cur[d], 1)] = sv.z;
        d = dv.w - base; if ((unsigned)d < (unsigned)HBINS) csr_src[atomicAdd(&cur[d], 1)] = sv.w;
    }
}

// ---------- Stage 5: H = bf16((X * rsqrt(out_deg)) @ W) via MFMA ----------
__global__ __launch_bounds__(256) void gemm_mfma(const float* __restrict__ X,
                                                 const int* __restrict__ deg_out,
                                                 const unsigned short* __restrict__ Wt,
                                                 unsigned short* __restrict__ H) {
    __shared__ char XsB[64 * 256];    // 64 rows x 128 bf16, swizzled (16KB)
    __shared__ char WsB[128 * 256];   // Wt[n][k] bf16, swizzled (32KB)
    int tid = threadIdx.x;
    int row0 = blockIdx.x * 64;

    for (int t = tid; t < 128 * 16; t += 256) {
        int n = t >> 4, o = t & 15;
        ushort8v wv = *reinterpret_cast<const ushort8v*>(Wt + n * DIM + o * 8);
        *reinterpret_cast<ushort8v*>(WsB + swz(n, o)) = wv;
    }
    for (int t = tid; t < 64 * 16; t += 256) {
        int r = t >> 4, o = t & 15;
        int node = row0 + r;
        float4 v0 = make_float4(0.f, 0.f, 0.f, 0.f), v1 = v0;
        float sc = 0.f;
        if (node < NODES) {
            const float4* rp = reinterpret_cast<const float4*>(X + (size_t)node * DIM);
            v0 = rp[o * 2];
            v1 = rp[o * 2 + 1];
            int dg = deg_out[node];
            sc = rsqrtf((float)(dg > 0 ? dg : 1));
        }
        ushort8v h;
        h[0] = f2bf(v0.x * sc); h[1] = f2bf(v0.y * sc);
        h[2] = f2bf(v0.z * sc); h[3] = f2bf(v0.w * sc);
        h[4] = f2bf(v1.x * sc); h[5] = f2bf(v1.y * sc);
        h[6] = f2bf(v1.z * sc); h[7] = f2bf(v1.w * sc);
        *reinterpret_cast<ushort8v*>(XsB + swz(r, o)) = h;
    }
    __syncthreads();

    int w = tid >> 6, l = tid & 63;
    int lr = l & 15, lg = l >> 4;
    f32x4 acc[8];
    #pragma unroll
    for (int nt = 0; nt < 8; ++nt) acc[nt] = (f32x4){0.f, 0.f, 0.f, 0.f};
    #pragma unroll
    for (int kb = 0; kb < 4; ++kb) {
        short8v a = *reinterpret_cast<short8v*>(XsB + swz(w * 16 + lr, kb * 4 + lg));
        #pragma unroll
        for (int nt = 0; nt < 8; ++nt) {
            short8v bfr = *reinterpret_cast<short8v*>(WsB + swz(nt * 16 + lr, kb * 4 + lg));
            acc[nt] = __builtin_amdgcn_mfma_f32_16x16x32_bf16(a, bfr, acc[nt], 0, 0, 0);
        }
    }
    #pragma unroll
    for (int nt = 0; nt < 8; ++nt) {
        int col = nt * 16 + lr;
        #pragma unroll
        for (int rg = 0; rg < 4; ++rg) {
            int m = w * 16 + lg * 4 + rg;
            int byte = m * 256 + (((col >> 3) ^ (m & 7)) << 4) + (col & 7) * 2;
            *reinterpret_cast<unsigned short*>(XsB + byte) = f2bf(acc[nt][rg]);
        }
    }
    __syncthreads();
    for (int t = tid; t < 64 * 16; t += 256) {
        int r = t >> 4, o = t & 15;
        int node = row0 + r;
        if (node < NODES)
            *reinterpret_cast<ushort8v*>(H + (size_t)node * DIM + o * 8) =
                *reinterpret_cast<ushort8v*>(XsB + swz(r, o));
    }
}

// ---------- Stage 6: out[n] = relu(rsqrt(in_deg)*sum H[src] + b) ----------
// One wave per node; 4x-unrolled independent load chain for latency hiding.
__global__ __launch_bounds__(256) void gather_kernel(const unsigned int* __restrict__ Hu,
                                                     const int* __restrict__ row_start,
                                                     const int* __restrict__ deg_in,
                                                     const int* __restrict__ csr_src,
                                                     const float* __restrict__ bias,
                                                     float* __restrict__ out) {
    int gw = (blockIdx.x * 256 + threadIdx.x) >> 6;
    int lane = threadIdx.x & 63;
    if (gw >= NODES) return;
    int start = row_start[gw];
    int deg = deg_in[gw];
    float ax = 0.f, ay = 0.f;
    for (int i0 = 0; i0 < deg; i0 += 64) {
        int nv = min(64, deg - i0);
        int sv = 0;
        if (i0 + lane < deg) sv = csr_src[start + i0 + lane];
        int i = 0;
        for (; i + 4 <= nv; i += 4) {
            int s0 = __shfl(sv, i, 64);
            int s1 = __shfl(sv, i + 1, 64);
            int s2 = __shfl(sv, i + 2, 64);
            int s3 = __shfl(sv, i + 3, 64);
            unsigned int u0 = Hu[(size_t)s0 * 64 + lane];
            unsigned int u1 = Hu[(size_t)s1 * 64 + lane];
            unsigned int u2 = Hu[(size_t)s2 * 64 + lane];
            unsigned int u3 = Hu[(size_t)s3 * 64 + lane];
            ax += __uint_as_float(u0 << 16);
            ay += __uint_as_float(u0 & 0xffff0000u);
            ax += __uint_as_float(u1 << 16);
            ay += __uint_as_float(u1 & 0xffff0000u);
            ax += __uint_as_float(u2 << 16);
            ay += __uint_as_float(u2 & 0xffff0000u);
            ax += __uint_as_float(u3 << 16);
            ay += __uint_as_float(u3 & 0xffff0000u);
        }
        for (; i < nv; ++i) {
            int s = __shfl(sv, i, 64);
            unsigned int u = Hu[(size_t)s * 64 + lane];
            ax += __uint_as_float(u << 16);
            ay += __uint_as_float(u & 0xffff0000u);
        }
    }
    float sc = rsqrtf((float)(deg > 0 ? deg : 1));
    float2 bb = reinterpret_cast<const float2*>(bias)[lane];
    float2 o;
    o.x = fmaxf(ax * sc + bb.x, 0.f);
    o.y = fmaxf(ay * sc + bb.y, 0.f);
    reinterpret_cast<float2*>(out)[(size_t)gw * 64 + lane] = o;
}

extern "C" void kernel_launch(void* const* d_in, const int* in_sizes, int n_in,
                              void* d_out, int out_size, void* d_ws, size_t ws_size,
                              hipStream_t stream) {
    const float* feat = (const float*)d_in[0];
    const float* W    = (const float*)d_in[1];
    const float* b    = (const float*)d_in[2];
    const int*   src  = (const int*)d_in[3];
    const int*   dst  = (const int*)d_in[4];
    float* out = (float*)d_out;

    constexpr size_t PART_ELEMS = (size_t)HRANGES * HC * HBINS;   // 2,293,760

    char* p = (char*)d_ws;
    // Region A: partial_src | partial_dst | cumoff (3x PART ushort = 13.76MB).
    // H (12.8MB) aliases this region — partial/cumoff are dead before gemm_mfma.
    unsigned short* partial = (unsigned short*)p;
    unsigned short* cumoff  = partial + 2 * PART_ELEMS;
    unsigned short* H       = (unsigned short*)p;
    p += 3 * PART_ELEMS * sizeof(unsigned short);
    unsigned short* Wt = (unsigned short*)p;  p += (size_t)DIM * DIM * 2;
    int* deg_out   = (int*)p;  p += (size_t)NODES * 4;
    int* deg_in    = (int*)p;  p += (size_t)NODES * 4;
    int* row_start = (int*)p;  p += (size_t)NODES * 4;
    int* scan_part = (int*)p;  p += 256;
    int* csr_src   = (int*)p;                                     // 2.4MB

    transpose_w<<<DIM * DIM / 256, 256, 0, stream>>>(W, Wt);
    hist_kernel<<<2 * HRANGES * HC, 256, 0, stream>>>(src, dst, partial);
    deg_coff<<<(HRANGES * HBINS) / 256, 256, 0, stream>>>(partial, deg_out, deg_in, cumoff);
    scan_partials<<<NB_SCAN, 256, 0, stream>>>(deg_in, scan_part);
    scan_chunks<<<NB_SCAN, 256, 0, stream>>>(deg_in, scan_part, row_start);
    bucket_lds<<<HRANGES * HC, 256, 0, stream>>>(src, dst, row_start, cumoff, csr_src);
    gemm_mfma<<<(NODES + 63) / 64, 256, 0, stream>>>(feat, deg_out, Wt, H);
    gather_kernel<<<(NODES * 64 + 255) / 256, 256, 0, stream>>>(
        (const unsigned int*)H, row_start, deg_in, csr_src, b, out);
}